// Round 3
// baseline (4368.139 us; speedup 1.0000x reference)
//
#include <hip/hip_runtime.h>
#include <math.h>

#define N_NODES 100000
#define N_EDGES 1600000

// ws layout (bytes):
//   [0, 400000)              dinv   float[N]   (deg counts, then rsqrt in-place)
//   [OFF_A, +51,200,000)     bufA   float[N*128]  (hs of current layer)
//   [OFF_B, +51,200,000)     bufB   float[N*128]  (agg of current layer)
// total ~102.8 MB
static constexpr size_t OFF_A = 401408;
static constexpr size_t OFF_B = OFF_A + 51200000;

__global__ __launch_bounds__(256) void k_deg(const int* __restrict__ dst,
                                             float* __restrict__ deg) {
    int i = blockIdx.x * 256 + threadIdx.x;
    if (i < N_EDGES) atomicAdd(&deg[dst[i]], 1.0f);
}

__global__ __launch_bounds__(256) void k_dinv(float* __restrict__ deg) {
    int i = blockIdx.x * 256 + threadIdx.x;
    if (i < N_NODES) deg[i] = rsqrtf(deg[i] + 1.0f);  // +1 = self loop; >=1 always
}

// Y[r, :] = dinv[r] * ( T(X[r, :]) @ W ), T = identity or relu(dinv*x + b1) (PRE)
// X is [N,128] always; W is [128,BN]; BM=64, BK=64, thread tile 4 rows x (BN/16) cols.
template<int BN, bool PRE>
__global__ __launch_bounds__(256) void k_gemm(
    const float* __restrict__ X, const float* __restrict__ W,
    const float* __restrict__ bpre, const float* __restrict__ dinv,
    float* __restrict__ Y)
{
    constexpr int JN = BN / 16;
    __shared__ __align__(16) float xs[64][68];   // +4 pad: breaks row-stride bank alias
    __shared__ __align__(16) float ws[64][BN];
    const int tid = threadIdx.x;
    const int tx = tid & 15, ty = tid >> 4;
    const long long row0 = (long long)blockIdx.x * 64;

    float acc[4][JN];
    #pragma unroll
    for (int i = 0; i < 4; ++i)
        #pragma unroll
        for (int j = 0; j < JN; ++j) acc[i][j] = 0.f;

    for (int k0 = 0; k0 < 128; k0 += 64) {
        // stage X tile: 64 rows x 64 cols; thread (ty,tx) loads float4 per pass
        #pragma unroll
        for (int p = 0; p < 4; ++p) {
            int r = p * 16 + ty;
            int c = tx * 4;
            long long gr = row0 + r;
            float4 v = make_float4(0.f, 0.f, 0.f, 0.f);
            if (gr < N_NODES) v = *(const float4*)&X[gr * 128 + k0 + c];
            if constexpr (PRE) {
                float dv = (gr < N_NODES) ? dinv[gr] : 0.f;
                const float4 bb = *(const float4*)&bpre[k0 + c];
                v.x = fmaxf(fmaf(dv, v.x, bb.x), 0.f);
                v.y = fmaxf(fmaf(dv, v.y, bb.y), 0.f);
                v.z = fmaxf(fmaf(dv, v.z, bb.z), 0.f);
                v.w = fmaxf(fmaf(dv, v.w, bb.w), 0.f);
            }
            *(float4*)&xs[r][c] = v;
        }
        // stage W tile: 64 rows x BN cols
        #pragma unroll
        for (int i4 = tid; i4 < 64 * BN / 4; i4 += 256) {
            int r = i4 / (BN / 4);
            int c = (i4 % (BN / 4)) * 4;
            *(float4*)&ws[r][c] = *(const float4*)&W[(k0 + r) * BN + c];
        }
        __syncthreads();
        #pragma unroll
        for (int kk = 0; kk < 64; ++kk) {
            float a[4];
            #pragma unroll
            for (int i = 0; i < 4; ++i) a[i] = xs[ty * 4 + i][kk];
            #pragma unroll
            for (int j = 0; j < JN; ++j) {
                float b = ws[kk][tx + 16 * j];   // lane-contiguous: conflict-free
                #pragma unroll
                for (int i = 0; i < 4; ++i) acc[i][j] = fmaf(a[i], b, acc[i][j]);
            }
        }
        __syncthreads();
    }
    #pragma unroll
    for (int i = 0; i < 4; ++i) {
        long long r = row0 + ty * 4 + i;
        if (r < N_NODES) {
            float dv = dinv[r];
            #pragma unroll
            for (int j = 0; j < JN; ++j)
                Y[r * BN + tx + 16 * j] = acc[i][j] * dv;   // coalesced across tx
        }
    }
}

// agg[dst,:] += hs[src,:], one float4 per thread, F4 float4s per edge
template<int F4>
__global__ __launch_bounds__(256) void k_scatter(
    const int* __restrict__ src, const int* __restrict__ dst,
    const float* __restrict__ hs, float* __restrict__ agg)
{
    int idx = blockIdx.x * 256 + threadIdx.x;   // max 51.2M, fits int
    if (idx >= N_EDGES * F4) return;
    int e = idx / F4;                            // F4 pow2 -> shift
    int q = idx - e * F4;
    int s = src[e];
    int d = dst[e];
    float4 v = *(const float4*)&hs[(long long)s * (F4 * 4) + q * 4];
    float* a = &agg[(long long)d * (F4 * 4) + q * 4];
    atomicAdd(a + 0, v.x);
    atomicAdd(a + 1, v.y);
    atomicAdd(a + 2, v.z);
    atomicAdd(a + 3, v.w);
}

// out[node,:] = log_softmax( relu(dinv*agg2 + b2) @ Wfc + bfc )
__global__ __launch_bounds__(256) void k_final(
    const float* __restrict__ agg2, const float* __restrict__ dinv,
    const float* __restrict__ b2, const float* __restrict__ Wfc,
    const float* __restrict__ bfc, float* __restrict__ out)
{
    __shared__ float wfc[64][16];
    __shared__ float sb2[64];
    __shared__ float sbfc[16];
    int tid = threadIdx.x;
    for (int i = tid; i < 64 * 16; i += 256) wfc[i >> 4][i & 15] = Wfc[i];
    if (tid < 64) sb2[tid] = b2[tid];
    if (tid < 16) sbfc[tid] = bfc[tid];
    __syncthreads();
    int node = blockIdx.x * 256 + tid;
    if (node >= N_NODES) return;
    float dv = dinv[node];
    float l[16];
    #pragma unroll
    for (int j = 0; j < 16; ++j) l[j] = sbfc[j];
    const float4* rowp = (const float4*)&agg2[(long long)node * 64];
    #pragma unroll
    for (int k4 = 0; k4 < 16; ++k4) {
        float4 v = rowp[k4];
        float h[4];
        h[0] = fmaxf(fmaf(dv, v.x, sb2[k4 * 4 + 0]), 0.f);
        h[1] = fmaxf(fmaf(dv, v.y, sb2[k4 * 4 + 1]), 0.f);
        h[2] = fmaxf(fmaf(dv, v.z, sb2[k4 * 4 + 2]), 0.f);
        h[3] = fmaxf(fmaf(dv, v.w, sb2[k4 * 4 + 3]), 0.f);
        #pragma unroll
        for (int u = 0; u < 4; ++u)
            #pragma unroll
            for (int j = 0; j < 16; ++j)
                l[j] = fmaf(h[u], wfc[k4 * 4 + u][j], l[j]);  // uniform idx: LDS broadcast
    }
    float m = l[0];
    #pragma unroll
    for (int j = 1; j < 16; ++j) m = fmaxf(m, l[j]);
    float sum = 0.f;
    #pragma unroll
    for (int j = 0; j < 16; ++j) sum += expf(l[j] - m);
    float ls = logf(sum);
    float* o = &out[(long long)node * 16];
    #pragma unroll
    for (int j = 0; j < 16; ++j) o[j] = l[j] - m - ls;
}

extern "C" void kernel_launch(void* const* d_in, const int* in_sizes, int n_in,
                              void* d_out, int out_size, void* d_ws, size_t ws_size,
                              hipStream_t stream) {
    const float* x   = (const float*)d_in[0];
    const int* ei    = (const int*)d_in[1];   // int32 [2, E] (harness: integer -> const int*)
    const float* W1  = (const float*)d_in[2];
    const float* b1  = (const float*)d_in[3];
    const float* W2  = (const float*)d_in[4];
    const float* b2  = (const float*)d_in[5];
    const float* Wfc = (const float*)d_in[6];
    const float* bfc = (const float*)d_in[7];
    float* out = (float*)d_out;

    char* ws = (char*)d_ws;
    float* dinv = (float*)ws;
    float* bufA = (float*)(ws + OFF_A);
    float* bufB = (float*)(ws + OFF_B);
    const int* src = ei;
    const int* dst = ei + N_EDGES;

    // degrees -> dinv
    hipMemsetAsync(dinv, 0, N_NODES * sizeof(float), stream);
    k_deg<<<(N_EDGES + 255) / 256, 256, 0, stream>>>(dst, dinv);
    k_dinv<<<(N_NODES + 255) / 256, 256, 0, stream>>>(dinv);

    // layer 1: hs1 = (x @ W1) * dinv  -> bufA
    k_gemm<128, false><<<(N_NODES + 63) / 64, 256, 0, stream>>>(x, W1, nullptr, dinv, bufA);
    // agg1 init with self-loop contribution, then scatter edges
    hipMemcpyAsync(bufB, bufA, (size_t)N_NODES * 128 * 4, hipMemcpyDeviceToDevice, stream);
    k_scatter<32><<<(N_EDGES * 32 + 255) / 256, 256, 0, stream>>>(src, dst, bufA, bufB);

    // layer 2: hs2 = (relu(dinv*agg1 + b1) @ W2) * dinv -> bufA[N,64]
    k_gemm<64, true><<<(N_NODES + 63) / 64, 256, 0, stream>>>(bufB, W2, b1, dinv, bufA);
    hipMemcpyAsync(bufB, bufA, (size_t)N_NODES * 64 * 4, hipMemcpyDeviceToDevice, stream);
    k_scatter<16><<<(N_EDGES * 16 + 255) / 256, 256, 0, stream>>>(src, dst, bufA, bufB);

    // final: relu(dinv*agg2 + b2) @ Wfc + bfc -> log_softmax -> out
    k_final<<<(N_NODES + 255) / 256, 256, 0, stream>>>(bufB, dinv, b2, Wfc, bfc, out);
}

// Round 4
// 601.395 us; speedup vs baseline: 7.2633x; 7.2633x over previous
//
#include <hip/hip_runtime.h>
#include <math.h>

#define N_NODES 100000
#define N_EDGES 1600000
#define NCHUNK 98   // ceil(N_NODES / 1024)

// ws layout (128B-aligned offsets):
static constexpr size_t OFF_CNT  = 0;                       // int[N]    degree histogram
static constexpr size_t OFF_DINV = 400384;                  // float[N]  rsqrt(deg+1)
static constexpr size_t OFF_ROW  = 800768;                  // int[N]    CSR row start
static constexpr size_t OFF_CUR  = 1201152;                 // int[N]    placement cursor
static constexpr size_t OFF_SPN  = 1601536;                 // int[256]  chunk spine
static constexpr size_t OFF_SSRC = 1602560;                 // int[E]    src sorted by dst
static constexpr size_t OFF_A    = 8003072;                 // float[N*128]
static constexpr size_t OFF_B    = OFF_A + 51200000;        // float[N*128]
// total = OFF_B + 51.2MB = 110.4 MB

__global__ __launch_bounds__(256) void k_hist(const int* __restrict__ dst,
                                              int* __restrict__ cnt) {
    int i = blockIdx.x * 256 + threadIdx.x;
    if (i < N_EDGES) atomicAdd(&cnt[dst[i]], 1);
}

__global__ __launch_bounds__(256) void k_dinv(const int* __restrict__ cnt,
                                              float* __restrict__ dinv) {
    int i = blockIdx.x * 256 + threadIdx.x;
    if (i < N_NODES) dinv[i] = rsqrtf((float)cnt[i] + 1.0f);  // +1 = self loop
}

// per-chunk sums (chunk = 1024 elems)
__global__ __launch_bounds__(256) void k_sum(const int* __restrict__ cnt,
                                             int* __restrict__ spn) {
    __shared__ int s[256];
    int chunk = blockIdx.x, t = threadIdx.x;
    int base = chunk * 1024 + t * 4;
    int v = 0;
    #pragma unroll
    for (int k = 0; k < 4; ++k) { int i = base + k; if (i < N_NODES) v += cnt[i]; }
    s[t] = v; __syncthreads();
    for (int off = 128; off > 0; off >>= 1) {
        if (t < off) s[t] += s[t + off];
        __syncthreads();
    }
    if (t == 0) spn[chunk] = s[0];
}

__global__ __launch_bounds__(64) void k_spine(int* __restrict__ spn) {
    if (threadIdx.x == 0) {
        int run = 0;
        for (int i = 0; i < NCHUNK; ++i) { int c = spn[i]; spn[i] = run; run += c; }
    }
}

// exclusive scan within each chunk + spine offset -> row_start; also init cursor
__global__ __launch_bounds__(256) void k_scan(const int* __restrict__ cnt,
                                              const int* __restrict__ spn,
                                              int* __restrict__ row,
                                              int* __restrict__ cur) {
    __shared__ int s[256];
    int chunk = blockIdx.x, t = threadIdx.x;
    int base = chunk * 1024 + t * 4;
    int v[4];
    #pragma unroll
    for (int k = 0; k < 4; ++k) { int i = base + k; v[k] = (i < N_NODES) ? cnt[i] : 0; }
    int tsum = v[0] + v[1] + v[2] + v[3];
    s[t] = tsum; __syncthreads();
    for (int off = 1; off < 256; off <<= 1) {          // Hillis-Steele inclusive
        int x = (t >= off) ? s[t - off] : 0;
        __syncthreads();
        s[t] += x;
        __syncthreads();
    }
    int excl = spn[chunk] + s[t] - tsum;
    int run = 0;
    #pragma unroll
    for (int k = 0; k < 4; ++k) {
        int i = base + k;
        if (i < N_NODES) { int o = excl + run; row[i] = o; cur[i] = o; }
        run += v[k];
    }
}

__global__ __launch_bounds__(256) void k_place(const int* __restrict__ src,
                                               const int* __restrict__ dst,
                                               int* __restrict__ cur,
                                               int* __restrict__ ssrc) {
    int e = blockIdx.x * 256 + threadIdx.x;
    if (e >= N_EDGES) return;
    int slot = atomicAdd(&cur[dst[e]], 1);
    ssrc[slot] = src[e];
}

// Y[r, :] = dinv[r] * ( T(X[r, :]) @ W ), T = identity or relu(dinv*x + b1) (PRE)
template<int BN, bool PRE>
__global__ __launch_bounds__(256) void k_gemm(
    const float* __restrict__ X, const float* __restrict__ W,
    const float* __restrict__ bpre, const float* __restrict__ dinv,
    float* __restrict__ Y)
{
    constexpr int JN = BN / 16;
    __shared__ __align__(16) float xs[64][68];
    __shared__ __align__(16) float ws[64][BN];
    const int tid = threadIdx.x;
    const int tx = tid & 15, ty = tid >> 4;
    const long long row0 = (long long)blockIdx.x * 64;

    float acc[4][JN];
    #pragma unroll
    for (int i = 0; i < 4; ++i)
        #pragma unroll
        for (int j = 0; j < JN; ++j) acc[i][j] = 0.f;

    for (int k0 = 0; k0 < 128; k0 += 64) {
        #pragma unroll
        for (int p = 0; p < 4; ++p) {
            int r = p * 16 + ty;
            int c = tx * 4;
            long long gr = row0 + r;
            float4 v = make_float4(0.f, 0.f, 0.f, 0.f);
            if (gr < N_NODES) v = *(const float4*)&X[gr * 128 + k0 + c];
            if constexpr (PRE) {
                float dv = (gr < N_NODES) ? dinv[gr] : 0.f;
                const float4 bb = *(const float4*)&bpre[k0 + c];
                v.x = fmaxf(fmaf(dv, v.x, bb.x), 0.f);
                v.y = fmaxf(fmaf(dv, v.y, bb.y), 0.f);
                v.z = fmaxf(fmaf(dv, v.z, bb.z), 0.f);
                v.w = fmaxf(fmaf(dv, v.w, bb.w), 0.f);
            }
            *(float4*)&xs[r][c] = v;
        }
        #pragma unroll
        for (int i4 = tid; i4 < 64 * BN / 4; i4 += 256) {
            int r = i4 / (BN / 4);
            int c = (i4 % (BN / 4)) * 4;
            *(float4*)&ws[r][c] = *(const float4*)&W[(k0 + r) * BN + c];
        }
        __syncthreads();
        #pragma unroll
        for (int kk = 0; kk < 64; ++kk) {
            float a[4];
            #pragma unroll
            for (int i = 0; i < 4; ++i) a[i] = xs[ty * 4 + i][kk];
            #pragma unroll
            for (int j = 0; j < JN; ++j) {
                float b = ws[kk][tx + 16 * j];
                #pragma unroll
                for (int i = 0; i < 4; ++i) acc[i][j] = fmaf(a[i], b, acc[i][j]);
            }
        }
        __syncthreads();
    }
    #pragma unroll
    for (int i = 0; i < 4; ++i) {
        long long r = row0 + ty * 4 + i;
        if (r < N_NODES) {
            float dv = dinv[r];
            #pragma unroll
            for (int j = 0; j < JN; ++j)
                Y[r * BN + tx + 16 * j] = acc[i][j] * dv;
        }
    }
}

// one wave per dst node: agg[d,:] = hs[d,:] + sum over edges hs[src,:]
// COLS=128: float2 per lane; COLS=64: float per lane.
template<int COLS>
__global__ __launch_bounds__(256) void k_gather(
    const int* __restrict__ ssrc, const int* __restrict__ row,
    const int* __restrict__ cnt, const float* __restrict__ hs,
    float* __restrict__ agg)
{
    const int node = (blockIdx.x * 256 + threadIdx.x) >> 6;   // uniform per wave
    const int lane = threadIdx.x & 63;
    if (node >= N_NODES) return;
    const int beg = row[node];
    const int num = cnt[node];

    if constexpr (COLS == 128) {
        const float2* hp = (const float2*)hs;
        float2 acc = hp[(size_t)node * 64 + lane];            // self loop
        for (int e0 = 0; e0 < num; e0 += 64) {
            int nb = num - e0; if (nb > 64) nb = 64;
            int sl = (e0 + lane < num) ? ssrc[beg + e0 + lane] : 0;
            int j = 0;
            for (; j + 4 <= nb; j += 4) {
                int s0 = __shfl(sl, j),     s1 = __shfl(sl, j + 1);
                int s2 = __shfl(sl, j + 2), s3 = __shfl(sl, j + 3);
                float2 a = hp[(size_t)s0 * 64 + lane];
                float2 b = hp[(size_t)s1 * 64 + lane];
                float2 c = hp[(size_t)s2 * 64 + lane];
                float2 d = hp[(size_t)s3 * 64 + lane];
                acc.x += a.x; acc.y += a.y; acc.x += b.x; acc.y += b.y;
                acc.x += c.x; acc.y += c.y; acc.x += d.x; acc.y += d.y;
            }
            for (; j < nb; ++j) {
                int s = __shfl(sl, j);
                float2 a = hp[(size_t)s * 64 + lane];
                acc.x += a.x; acc.y += a.y;
            }
        }
        ((float2*)agg)[(size_t)node * 64 + lane] = acc;
    } else {
        float acc = hs[(size_t)node * 64 + lane];             // self loop
        for (int e0 = 0; e0 < num; e0 += 64) {
            int nb = num - e0; if (nb > 64) nb = 64;
            int sl = (e0 + lane < num) ? ssrc[beg + e0 + lane] : 0;
            int j = 0;
            for (; j + 4 <= nb; j += 4) {
                int s0 = __shfl(sl, j),     s1 = __shfl(sl, j + 1);
                int s2 = __shfl(sl, j + 2), s3 = __shfl(sl, j + 3);
                float a = hs[(size_t)s0 * 64 + lane];
                float b = hs[(size_t)s1 * 64 + lane];
                float c = hs[(size_t)s2 * 64 + lane];
                float d = hs[(size_t)s3 * 64 + lane];
                acc += a; acc += b; acc += c; acc += d;
            }
            for (; j < nb; ++j) {
                int s = __shfl(sl, j);
                acc += hs[(size_t)s * 64 + lane];
            }
        }
        agg[(size_t)node * 64 + lane] = acc;
    }
}

// out[node,:] = log_softmax( relu(dinv*agg2 + b2) @ Wfc + bfc )
__global__ __launch_bounds__(256) void k_final(
    const float* __restrict__ agg2, const float* __restrict__ dinv,
    const float* __restrict__ b2, const float* __restrict__ Wfc,
    const float* __restrict__ bfc, float* __restrict__ out)
{
    __shared__ float wfc[64][16];
    __shared__ float sb2[64];
    __shared__ float sbfc[16];
    int tid = threadIdx.x;
    for (int i = tid; i < 64 * 16; i += 256) wfc[i >> 4][i & 15] = Wfc[i];
    if (tid < 64) sb2[tid] = b2[tid];
    if (tid < 16) sbfc[tid] = bfc[tid];
    __syncthreads();
    int node = blockIdx.x * 256 + tid;
    if (node >= N_NODES) return;
    float dv = dinv[node];
    float l[16];
    #pragma unroll
    for (int j = 0; j < 16; ++j) l[j] = sbfc[j];
    const float4* rowp = (const float4*)&agg2[(long long)node * 64];
    #pragma unroll
    for (int k4 = 0; k4 < 16; ++k4) {
        float4 v = rowp[k4];
        float h[4];
        h[0] = fmaxf(fmaf(dv, v.x, sb2[k4 * 4 + 0]), 0.f);
        h[1] = fmaxf(fmaf(dv, v.y, sb2[k4 * 4 + 1]), 0.f);
        h[2] = fmaxf(fmaf(dv, v.z, sb2[k4 * 4 + 2]), 0.f);
        h[3] = fmaxf(fmaf(dv, v.w, sb2[k4 * 4 + 3]), 0.f);
        #pragma unroll
        for (int u = 0; u < 4; ++u)
            #pragma unroll
            for (int j = 0; j < 16; ++j)
                l[j] = fmaf(h[u], wfc[k4 * 4 + u][j], l[j]);
    }
    float m = l[0];
    #pragma unroll
    for (int j = 1; j < 16; ++j) m = fmaxf(m, l[j]);
    float sum = 0.f;
    #pragma unroll
    for (int j = 0; j < 16; ++j) sum += expf(l[j] - m);
    float ls = logf(sum);
    float* o = &out[(long long)node * 16];
    #pragma unroll
    for (int j = 0; j < 16; ++j) o[j] = l[j] - m - ls;
}

extern "C" void kernel_launch(void* const* d_in, const int* in_sizes, int n_in,
                              void* d_out, int out_size, void* d_ws, size_t ws_size,
                              hipStream_t stream) {
    const float* x   = (const float*)d_in[0];
    const int* ei    = (const int*)d_in[1];   // int32 [2, E]
    const float* W1  = (const float*)d_in[2];
    const float* b1  = (const float*)d_in[3];
    const float* W2  = (const float*)d_in[4];
    const float* b2  = (const float*)d_in[5];
    const float* Wfc = (const float*)d_in[6];
    const float* bfc = (const float*)d_in[7];
    float* out = (float*)d_out;

    char* ws = (char*)d_ws;
    int*   cnt  = (int*)(ws + OFF_CNT);
    float* dinv = (float*)(ws + OFF_DINV);
    int*   row  = (int*)(ws + OFF_ROW);
    int*   cur  = (int*)(ws + OFF_CUR);
    int*   spn  = (int*)(ws + OFF_SPN);
    int*   ssrc = (int*)(ws + OFF_SSRC);
    float* bufA = (float*)(ws + OFF_A);
    float* bufB = (float*)(ws + OFF_B);
    const int* src = ei;
    const int* dst = ei + N_EDGES;

    // ---- CSR build (by dst) + dinv ----
    hipMemsetAsync(cnt, 0, N_NODES * sizeof(int), stream);
    k_hist<<<(N_EDGES + 255) / 256, 256, 0, stream>>>(dst, cnt);
    k_dinv<<<(N_NODES + 255) / 256, 256, 0, stream>>>(cnt, dinv);
    k_sum<<<NCHUNK, 256, 0, stream>>>(cnt, spn);
    k_spine<<<1, 64, 0, stream>>>(spn);
    k_scan<<<NCHUNK, 256, 0, stream>>>(cnt, spn, row, cur);
    k_place<<<(N_EDGES + 255) / 256, 256, 0, stream>>>(src, dst, cur, ssrc);

    // ---- layer 1: hs1 = (x @ W1) * dinv -> bufA; agg1 -> bufB ----
    k_gemm<128, false><<<(N_NODES + 63) / 64, 256, 0, stream>>>(x, W1, nullptr, dinv, bufA);
    k_gather<128><<<(N_NODES * 64) / 256, 256, 0, stream>>>(ssrc, row, cnt, bufA, bufB);

    // ---- layer 2: hs2 = (relu(dinv*agg1 + b1) @ W2) * dinv -> bufA; agg2 -> bufB ----
    k_gemm<64, true><<<(N_NODES + 63) / 64, 256, 0, stream>>>(bufB, W2, b1, dinv, bufA);
    k_gather<64><<<(N_NODES * 64) / 256, 256, 0, stream>>>(ssrc, row, cnt, bufA, bufB);

    // ---- final: relu(dinv*agg2 + b2) @ Wfc + bfc -> log_softmax ----
    k_final<<<(N_NODES + 255) / 256, 256, 0, stream>>>(bufB, dinv, b2, Wfc, bfc, out);
}